// Round 1
// 737.439 us; speedup vs baseline: 1.0461x; 1.0461x over previous
//
#include <hip/hip_runtime.h>
#include <math.h>

#define DIMC 192
#define DIN 384
#define XZC 768
#define NPROJ 14
#define PSTR 16
#define LSEQ 9216
#define NBATCH 16
#define NTOK (NBATCH*LSEQ)     // 147456
#define CHUNK 128
#define NCH (LSEQ/CHUNK)       // 72

typedef unsigned short u16;
typedef unsigned int u32;
typedef __attribute__((ext_vector_type(8))) short bf16x8;
typedef __attribute__((ext_vector_type(4))) float f32x4;

__device__ __forceinline__ float bf2f(u16 a){
  union { u32 u; float f; } v; v.u = ((u32)a)<<16; return v.f;
}
__device__ __forceinline__ u16 f2bf(float f){
  union { u32 u; float f; } v; v.f = f;
  u32 r = v.u + 0x7FFFu + ((v.u>>16)&1u);
  return (u16)(r>>16);
}
__device__ __forceinline__ float frcp(float x){ return __builtin_amdgcn_rcpf(x); }
__device__ __forceinline__ float softplus_f(float x){
  return fmaxf(x, 0.f) + __logf(1.f + __expf(-fabsf(x)));
}
__device__ __forceinline__ float silu_f(float a){
  return a * frcp(1.f + __expf(-a));
}

// ---------------- weight packing ----------------
// Bp1: W_in (192x768) packed in B-fragment order for 16x16x32 MFMA:
//   Bp1[((nt*6+ks)*64+lane)*8+j] = Win[(ks*32+(lane>>4)*8+j)*XZC + nt*16+(lane&15)]
// Bp2: W_out (384x192) likewise with 12 ksteps.
// Wxp: Wx in B-frag order (N=16 pad). cwT[tap][384]: transposed conv weights.
__global__ void k_convert(const float* __restrict__ Win, const float* __restrict__ Wout,
                          const float* __restrict__ Wx, const float* __restrict__ cw,
                          u16* __restrict__ Bp1, u16* __restrict__ Bp2,
                          u16* __restrict__ Wxp, float* __restrict__ cwT){
  int i = blockIdx.x*256 + threadIdx.x;
  if (i < XZC*DIMC){          // 147456
    int j = i&7, lane = (i>>3)&63, rest = i>>9;
    int ks = rest%6, nt = rest/6;
    int k = ks*32 + (lane>>4)*8 + j, n = nt*16 + (lane&15);
    Bp1[i] = f2bf(Win[(size_t)k*XZC + n]);
  }
  if (i < DIN*DIMC){          // 73728
    int j = i&7, lane = (i>>3)&63, rest = i>>9;
    int ks = rest%12, nt = rest/12;
    int k = ks*32 + (lane>>4)*8 + j, n = nt*16 + (lane&15);
    Bp2[i] = f2bf(Wout[(size_t)k*DIMC + n]);
  }
  if (i < 12*4*16*8){
    int j = i&7, n = (i>>3)&15, quad = (i>>7)&3, kstep = i>>9;
    int k = kstep*32 + quad*8 + j;
    Wxp[i] = (n < NPROJ) ? f2bf(Wx[k*NPROJ + n]) : (u16)0;
  }
  if (i < 3*DIN){
    int tap = i / DIN, ch = i - tap*DIN;
    cwT[i] = cw[ch*3 + tap];
  }
}

// ---------------- fused LayerNorm + GEMM1 (register-direct MFMA, no LDS) ----------------
// wave = 32 tokens (2 sets of 16). Each B-fragment load feeds 2 MFMAs so
// L2 B-traffic halves and load latency hides under the paired MFMA.
__global__ __launch_bounds__(256) void k_lngemm1(const float* __restrict__ x,
        const float* __restrict__ lnw, const float* __restrict__ lnb,
        const u16* __restrict__ Bp1, u16* __restrict__ xB, u16* __restrict__ zB)
{
  int tid = threadIdx.x, wv = tid>>6, lane = tid&63;
  int lr = lane&15, lq = lane>>4;
  int tokw = blockIdx.x*128 + wv*32;
  bf16x8 af[2][6];
  #pragma unroll
  for (int s=0;s<2;++s){
    int token = tokw + s*16 + lr;
    const float* xp = x + (size_t)token*DIMC + lq*8;
    float v[48];
    #pragma unroll
    for (int ks=0;ks<6;++ks){
      float4 a = *(const float4*)(xp + ks*32);
      float4 b = *(const float4*)(xp + ks*32 + 4);
      v[ks*8+0]=a.x; v[ks*8+1]=a.y; v[ks*8+2]=a.z; v[ks*8+3]=a.w;
      v[ks*8+4]=b.x; v[ks*8+5]=b.y; v[ks*8+6]=b.z; v[ks*8+7]=b.w;
    }
    float sm = 0.f;
    #pragma unroll
    for (int j=0;j<48;++j) sm += v[j];
    sm += __shfl_xor(sm, 16); sm += __shfl_xor(sm, 32);
    float mu = sm * (1.0f/DIMC);
    float q = 0.f;
    #pragma unroll
    for (int j=0;j<48;++j){ float d = v[j]-mu; q += d*d; }
    q += __shfl_xor(q, 16); q += __shfl_xor(q, 32);
    float rstd = rsqrtf(q*(1.0f/DIMC) + 1e-5f);
    #pragma unroll
    for (int ks=0;ks<6;++ks){
      const float* wp = lnw + lq*8 + ks*32;
      const float* bp = lnb + lq*8 + ks*32;
      float4 w0 = *(const float4*)(wp),   w1 = *(const float4*)(wp+4);
      float4 b0 = *(const float4*)(bp),   b1 = *(const float4*)(bp+4);
      float wj[8] = {w0.x,w0.y,w0.z,w0.w,w1.x,w1.y,w1.z,w1.w};
      float bj[8] = {b0.x,b0.y,b0.z,b0.w,b1.x,b1.y,b1.z,b1.w};
      #pragma unroll
      for (int j=0;j<8;++j)
        af[s][ks][j] = (short)f2bf((v[ks*8+j]-mu)*rstd*wj[j] + bj[j]);
    }
  }
  #pragma unroll 2
  for (int nt=0; nt<48; ++nt){
    f32x4 acc0 = (f32x4){0.f,0.f,0.f,0.f};
    f32x4 acc1 = (f32x4){0.f,0.f,0.f,0.f};
    #pragma unroll
    for (int ks=0;ks<6;++ks){
      bf16x8 bf_ = *(const bf16x8*)(Bp1 + (size_t)((nt*6+ks)<<9) + (size_t)lane*8);
      acc0 = __builtin_amdgcn_mfma_f32_16x16x32_bf16(af[0][ks], bf_, acc0, 0,0,0);
      acc1 = __builtin_amdgcn_mfma_f32_16x16x32_bf16(af[1][ks], bf_, acc1, 0,0,0);
    }
    int col = nt*16 + lr;
    u16* base = (col < DIN) ? xB : zB;
    int cc = (col < DIN) ? col : col - DIN;
    #pragma unroll
    for (int r=0;r<4;++r){
      int row0 = tokw + lq*4 + r;
      base[(size_t)row0*DIN + cc]      = f2bf(acc0[r]);
      base[(size_t)(row0+16)*DIN + cc] = f2bf(acc1[r]);
    }
  }
}

// ---------------- conv3 + SiLU + MFMA projection ----------------
__global__ __launch_bounds__(256) void k_conv(const u16* __restrict__ xB,
        const float* __restrict__ cwT, const float* __restrict__ cb,
        const u16* __restrict__ Wxp, float* __restrict__ proj){
  int tid = threadIdx.x, wv = tid>>6, lane = tid&63;
  int lr = lane&15, lq = lane>>4;
  int tok0 = blockIdx.x*64 + wv*16;
  int token = tok0 + lr;
  int l = token % LSEQ;
  float m1 = (l>=1)?1.f:0.f, m2 = (l>=2)?1.f:0.f;
  int tm1 = (l>=1)? token-1 : token;
  int tm2 = (l>=2)? token-2 : token;
  bf16x8 bfrag[12];
  #pragma unroll
  for (int ks=0;ks<12;++ks)
    bfrag[ks] = *(const bf16x8*)(Wxp + (size_t)ks*512 + (size_t)lane*8);
  f32x4 acc = (f32x4){0.f,0.f,0.f,0.f};
  #pragma unroll
  for (int ks=0;ks<12;++ks){
    int ch0 = ks*32 + lq*8;
    bf16x8 x0 = *(const bf16x8*)(xB + (size_t)token*DIN + ch0);
    bf16x8 x1 = *(const bf16x8*)(xB + (size_t)tm1*DIN + ch0);
    bf16x8 x2 = *(const bf16x8*)(xB + (size_t)tm2*DIN + ch0);
    const float* w2 = cwT + 2*DIN + ch0;
    const float* w1 = cwT + 1*DIN + ch0;
    const float* w0 = cwT + 0*DIN + ch0;
    const float* cbp = cb + ch0;
    bf16x8 af;
    #pragma unroll
    for (int j=0;j<8;++j){
      float a = cbp[j] + w2[j]*bf2f((u16)x0[j])
                       + (w1[j]*m1)*bf2f((u16)x1[j])
                       + (w0[j]*m2)*bf2f((u16)x2[j]);
      af[j] = (short)f2bf(silu_f(a));
    }
    acc = __builtin_amdgcn_mfma_f32_16x16x32_bf16(af, bfrag[ks], acc, 0,0,0);
  }
  #pragma unroll
  for (int r=0;r<4;++r){
    int row = lq*4 + r;
    proj[(size_t)(tok0+row)*PSTR + lr] = acc[r];
  }
}

// ---------------- scan pass 1 ----------------
__global__ __launch_bounds__(384) void k_scan1(const float* __restrict__ proj, const u16* __restrict__ xB,
    const float* __restrict__ cw, const float* __restrict__ cb,
    const float* __restrict__ Wdt, const float* __restrict__ bdt, const float* __restrict__ Alog,
    float* __restrict__ Pg, float* __restrict__ Hg){
  __shared__ __align__(16) float ps[CHUNK*PSTR];
  int b = blockIdx.y, ch = blockIdx.x, d = threadIdx.x;
  int tok0 = b*LSEQ + ch*CHUNK;
  {
    const float4* src = (const float4*)(proj + (size_t)tok0*PSTR);
    float4* dst = (float4*)ps;
    for (int i = d; i < CHUNK*PSTR/4; i += 384) dst[i] = src[i];
  }
  __syncthreads();
  float wdt[12];
  #pragma unroll
  for (int r=0;r<12;++r) wdt[r] = Wdt[r*DIN+d];
  float bd = bdt[d];
  float Av = -__expf(Alog[d]);
  float c0=cw[d*3], c1=cw[d*3+1], c2=cw[d*3+2], cbv=cb[d];
  float xm1=0.f, xm2=0.f;
  if (ch > 0){
    xm1 = bf2f(xB[(size_t)(tok0-1)*DIN + d]);
    xm2 = bf2f(xB[(size_t)(tok0-2)*DIN + d]);
  }
  float h = 0.f, P = 1.f;
  #pragma unroll 4
  for (int il=0; il<CHUNK; ++il){
    float xc = bf2f(xB[(size_t)(tok0+il)*DIN + d]);
    const float4* pq = (const float4*)(ps + il*PSTR);
    float4 q0=pq[0], q1=pq[1], q2=pq[2], q3=pq[3];
    float a = cbv + c2*xc + c1*xm1 + c0*xm2;
    float uu = silu_f(a);
    float xv = bd + q0.x*wdt[0]+q0.y*wdt[1]+q0.z*wdt[2]+q0.w*wdt[3]
                  + q1.x*wdt[4]+q1.y*wdt[5]+q1.z*wdt[6]+q1.w*wdt[7]
                  + q2.x*wdt[8]+q2.y*wdt[9]+q2.z*wdt[10]+q2.w*wdt[11];
    float dt = softplus_f(xv);
    float dA = __expf(dt*Av);
    h = dA*h + dt*q3.x*uu;
    P *= dA;
    xm2 = xm1; xm1 = xc;
  }
  int o = (b*NCH + ch)*DIN + d;
  Pg[o] = P; Hg[o] = h;
}

// ---------------- scan pass 2 ----------------
__global__ void k_scan2(const float* __restrict__ Pg, const float* __restrict__ Hg,
                        float* __restrict__ hin){
  int idx = blockIdx.x*256 + threadIdx.x;
  int b = idx/DIN, d = idx - b*DIN;
  float run = 0.f;
  #pragma unroll 4
  for (int ch=0; ch<NCH; ++ch){
    int o = (b*NCH+ch)*DIN + d;
    hin[o] = run;
    run = Pg[o]*run + Hg[o];
  }
}

// ---------------- scan pass 3 ----------------
__global__ __launch_bounds__(384) void k_scan3(const float* __restrict__ proj, const u16* __restrict__ xB,
    const float* __restrict__ cw, const float* __restrict__ cb,
    const float* __restrict__ Wdt, const float* __restrict__ bdt,
    const float* __restrict__ Alog, const float* __restrict__ Dp,
    const float* __restrict__ hin, u16* __restrict__ zB){
  __shared__ __align__(16) float ps[CHUNK*PSTR];
  int b = blockIdx.y, ch = blockIdx.x, d = threadIdx.x;
  int tok0 = b*LSEQ + ch*CHUNK;
  {
    const float4* src = (const float4*)(proj + (size_t)tok0*PSTR);
    float4* dst = (float4*)ps;
    for (int i = d; i < CHUNK*PSTR/4; i += 384) dst[i] = src[i];
  }
  __syncthreads();
  float wdt[12];
  #pragma unroll
  for (int r=0;r<12;++r) wdt[r] = Wdt[r*DIN+d];
  float bd = bdt[d];
  float Av = -__expf(Alog[d]);
  float Dv = Dp[d];
  float c0=cw[d*3], c1=cw[d*3+1], c2=cw[d*3+2], cbv=cb[d];
  float xm1=0.f, xm2=0.f;
  if (ch > 0){
    xm1 = bf2f(xB[(size_t)(tok0-1)*DIN + d]);
    xm2 = bf2f(xB[(size_t)(tok0-2)*DIN + d]);
  }
  float h = hin[(b*NCH+ch)*DIN + d];
  #pragma unroll 4
  for (int il=0; il<CHUNK; ++il){
    float xc = bf2f(xB[(size_t)(tok0+il)*DIN + d]);
    const float4* pq = (const float4*)(ps + il*PSTR);
    float4 q0=pq[0], q1=pq[1], q2=pq[2], q3=pq[3];
    float a = cbv + c2*xc + c1*xm1 + c0*xm2;
    float uu = silu_f(a);
    float xv = bd + q0.x*wdt[0]+q0.y*wdt[1]+q0.z*wdt[2]+q0.w*wdt[3]
                  + q1.x*wdt[4]+q1.y*wdt[5]+q1.z*wdt[6]+q1.w*wdt[7]
                  + q2.x*wdt[8]+q2.y*wdt[9]+q2.z*wdt[10]+q2.w*wdt[11];
    float dt = softplus_f(xv);
    float dA = __expf(dt*Av);
    h = dA*h + dt*q3.x*uu;
    size_t zo = (size_t)(tok0+il)*DIN + d;
    float zz = bf2f(zB[zo]);
    zB[zo] = f2bf((h*q3.y + uu*Dv)*silu_f(zz));
    xm2 = xm1; xm1 = xc;
  }
}

// ---------------- GEMM2 (register-direct MFMA, 2 token-sets/wave): out = y @ W_out + x ----------------
__global__ __launch_bounds__(256) void k_gemm2(const u16* __restrict__ A, const u16* __restrict__ Bp2,
        const float* __restrict__ R, float* __restrict__ C)
{
  int tid = threadIdx.x, wv = tid>>6, lane = tid&63;
  int lr = lane&15, lq = lane>>4;
  int tokw = blockIdx.x*128 + wv*32;
  int t0 = tokw + lr, t1 = tokw + 16 + lr;
  bf16x8 af0[12], af1[12];
  #pragma unroll
  for (int ks=0;ks<12;++ks){
    af0[ks] = *(const bf16x8*)(A + (size_t)t0*DIN + ks*32 + lq*8);
    af1[ks] = *(const bf16x8*)(A + (size_t)t1*DIN + ks*32 + lq*8);
  }
  #pragma unroll 2
  for (int nt=0; nt<12; ++nt){
    f32x4 acc0 = (f32x4){0.f,0.f,0.f,0.f};
    f32x4 acc1 = (f32x4){0.f,0.f,0.f,0.f};
    #pragma unroll
    for (int ks=0;ks<12;++ks){
      bf16x8 bf_ = *(const bf16x8*)(Bp2 + (size_t)((nt*12+ks)<<9) + (size_t)lane*8);
      acc0 = __builtin_amdgcn_mfma_f32_16x16x32_bf16(af0[ks], bf_, acc0, 0,0,0);
      acc1 = __builtin_amdgcn_mfma_f32_16x16x32_bf16(af1[ks], bf_, acc1, 0,0,0);
    }
    int col = nt*16 + lr;
    #pragma unroll
    for (int r=0;r<4;++r){
      int row = tokw + lq*4 + r;
      size_t o0 = (size_t)row*DIMC + col;
      size_t o1 = (size_t)(row+16)*DIMC + col;
      C[o0] = acc0[r] + R[o0];
      C[o1] = acc1[r] + R[o1];
    }
  }
}

// ---------------- launch ----------------
extern "C" void kernel_launch(void* const* d_in, const int* in_sizes, int n_in,
                              void* d_out, int out_size, void* d_ws, size_t ws_size,
                              hipStream_t stream) {
  const float* x     = (const float*)d_in[0];
  const float* lnw   = (const float*)d_in[1];
  const float* lnb   = (const float*)d_in[2];
  const float* Win   = (const float*)d_in[3];
  const float* convw = (const float*)d_in[4];
  const float* convb = (const float*)d_in[5];
  const float* Wx    = (const float*)d_in[6];
  const float* Wdt   = (const float*)d_in[7];
  const float* bdt   = (const float*)d_in[8];
  const float* Alog  = (const float*)d_in[9];
  const float* Dp    = (const float*)d_in[10];
  const float* Wout  = (const float*)d_in[11];
  float* out = (float*)d_out;

  char* ws = (char*)d_ws;
  size_t off = 0;
  auto alloc = [&](size_t bytes){ size_t r = off; off += (bytes + 255) & ~(size_t)255; return r; };
  u16*   xB    = (u16*)  (ws + alloc((size_t)NTOK*DIN*2));
  u16*   zB    = (u16*)  (ws + alloc((size_t)NTOK*DIN*2));
  float* proj  = (float*)(ws + alloc((size_t)NTOK*PSTR*4));
  u16*   Bp1   = (u16*)  (ws + alloc((size_t)XZC*DIMC*2));
  u16*   Bp2   = (u16*)  (ws + alloc((size_t)DIN*DIMC*2));
  u16*   Wxp   = (u16*)  (ws + alloc((size_t)12*4*16*8*2));
  float* cwT   = (float*)(ws + alloc((size_t)3*DIN*4));
  float* Pg    = (float*)(ws + alloc((size_t)NBATCH*NCH*DIN*4));
  float* Hg    = (float*)(ws + alloc((size_t)NBATCH*NCH*DIN*4));
  float* hin   = (float*)(ws + alloc((size_t)NBATCH*NCH*DIN*4));

  k_convert<<<576, 256, 0, stream>>>(Win, Wout, Wx, convw, Bp1, Bp2, Wxp, cwT);
  k_lngemm1<<<NTOK/128, 256, 0, stream>>>(x, lnw, lnb, Bp1, xB, zB);
  k_conv<<<NTOK/64, 256, 0, stream>>>(xB, cwT, convb, Wxp, proj);
  {
    dim3 g(NCH, NBATCH);
    k_scan1<<<g, 384, 0, stream>>>(proj, xB, convw, convb, Wdt, bdt, Alog, Pg, Hg);
  }
  k_scan2<<<24, 256, 0, stream>>>(Pg, Hg, hin);
  {
    dim3 g(NCH, NBATCH);
    k_scan3<<<g, 384, 0, stream>>>(proj, xB, convw, convb, Wdt, bdt, Alog, Dp, hin, zB);
  }
  k_gemm2<<<NTOK/128, 256, 0, stream>>>(zB, Bp2, x, out);
}

// Round 2
// 670.852 us; speedup vs baseline: 1.1500x; 1.0993x over previous
//
#include <hip/hip_runtime.h>
#include <math.h>

#define DIMC 192
#define DIN 384
#define XZC 768
#define NPROJ 14
#define PSTR 16
#define LSEQ 9216
#define NBATCH 16
#define NTOK (NBATCH*LSEQ)     // 147456
#define CHUNK 128
#define NCH (LSEQ/CHUNK)       // 72

typedef unsigned short u16;
typedef unsigned int u32;
typedef __attribute__((ext_vector_type(8))) short bf16x8;
typedef __attribute__((ext_vector_type(4))) float f32x4;

#define AS1 __attribute__((address_space(1)))
#define AS3 __attribute__((address_space(3)))

__device__ __forceinline__ float bf2f(u16 a){
  union { u32 u; float f; } v; v.u = ((u32)a)<<16; return v.f;
}
__device__ __forceinline__ u16 f2bf(float f){
  union { u32 u; float f; } v; v.f = f;
  u32 r = v.u + 0x7FFFu + ((v.u>>16)&1u);
  return (u16)(r>>16);
}
__device__ __forceinline__ float frcp(float x){ return __builtin_amdgcn_rcpf(x); }
__device__ __forceinline__ float softplus_f(float x){
  return fmaxf(x, 0.f) + __logf(1.f + __expf(-fabsf(x)));
}
__device__ __forceinline__ float silu_f(float a){
  return a * frcp(1.f + __expf(-a));
}

// ---------------- weight packing ----------------
// Bp1: W_in (192x768) packed in B-fragment order for 16x16x32 MFMA:
//   Bp1[((nt*6+ks)*64+lane)*8+j] = Win[(ks*32+(lane>>4)*8+j)*XZC + nt*16+(lane&15)]
// Bp2: W_out (384x192) likewise with 12 ksteps.
// Wxp: Wx in B-frag order (N=16 pad). cwT[tap][384]: transposed conv weights.
__global__ void k_convert(const float* __restrict__ Win, const float* __restrict__ Wout,
                          const float* __restrict__ Wx, const float* __restrict__ cw,
                          u16* __restrict__ Bp1, u16* __restrict__ Bp2,
                          u16* __restrict__ Wxp, float* __restrict__ cwT){
  int i = blockIdx.x*256 + threadIdx.x;
  if (i < XZC*DIMC){          // 147456
    int j = i&7, lane = (i>>3)&63, rest = i>>9;
    int ks = rest%6, nt = rest/6;
    int k = ks*32 + (lane>>4)*8 + j, n = nt*16 + (lane&15);
    Bp1[i] = f2bf(Win[(size_t)k*XZC + n]);
  }
  if (i < DIN*DIMC){          // 73728
    int j = i&7, lane = (i>>3)&63, rest = i>>9;
    int ks = rest%12, nt = rest/12;
    int k = ks*32 + (lane>>4)*8 + j, n = nt*16 + (lane&15);
    Bp2[i] = f2bf(Wout[(size_t)k*DIMC + n]);
  }
  if (i < 12*4*16*8){
    int j = i&7, n = (i>>3)&15, quad = (i>>7)&3, kstep = i>>9;
    int k = kstep*32 + quad*8 + j;
    Wxp[i] = (n < NPROJ) ? f2bf(Wx[k*NPROJ + n]) : (u16)0;
  }
  if (i < 3*DIN){
    int tap = i / DIN, ch = i - tap*DIN;
    cwT[i] = cw[ch*3 + tap];
  }
}

// ---------------- fused LayerNorm + GEMM1 (LDS-staged B, 8 waves, 2 sets/wave) ----------------
// Block = 512 thr = 8 waves = 256 tokens. B (294KB) streamed through 48KB LDS
// chunks via global_load_lds; all 8 waves share each staged chunk (8x less
// L2 traffic than register-direct, ds_read latency instead of L2 latency).
__global__ __launch_bounds__(512) void k_lngemm1(const float* __restrict__ x,
        const float* __restrict__ lnw, const float* __restrict__ lnb,
        const u16* __restrict__ Bp1, u16* __restrict__ xB, u16* __restrict__ zB)
{
  __shared__ __align__(16) char smem[49152];
  int tid = threadIdx.x, wv = tid>>6, lane = tid&63;
  int lr = lane&15, lq = lane>>4;
  int tokw = blockIdx.x*256 + wv*32;
  bf16x8 af[2][6];
  #pragma unroll
  for (int s=0;s<2;++s){
    int token = tokw + s*16 + lr;
    const float* xp = x + (size_t)token*DIMC + lq*8;
    float v[48];
    #pragma unroll
    for (int ks=0;ks<6;++ks){
      float4 a = *(const float4*)(xp + ks*32);
      float4 b = *(const float4*)(xp + ks*32 + 4);
      v[ks*8+0]=a.x; v[ks*8+1]=a.y; v[ks*8+2]=a.z; v[ks*8+3]=a.w;
      v[ks*8+4]=b.x; v[ks*8+5]=b.y; v[ks*8+6]=b.z; v[ks*8+7]=b.w;
    }
    float sm = 0.f;
    #pragma unroll
    for (int j=0;j<48;++j) sm += v[j];
    sm += __shfl_xor(sm, 16); sm += __shfl_xor(sm, 32);
    float mu = sm * (1.0f/DIMC);
    float q = 0.f;
    #pragma unroll
    for (int j=0;j<48;++j){ float d = v[j]-mu; q += d*d; }
    q += __shfl_xor(q, 16); q += __shfl_xor(q, 32);
    float rstd = rsqrtf(q*(1.0f/DIMC) + 1e-5f);
    #pragma unroll
    for (int ks=0;ks<6;++ks){
      const float* wp = lnw + lq*8 + ks*32;
      const float* bp = lnb + lq*8 + ks*32;
      float4 w0 = *(const float4*)(wp),   w1 = *(const float4*)(wp+4);
      float4 b0 = *(const float4*)(bp),   b1 = *(const float4*)(bp+4);
      float wj[8] = {w0.x,w0.y,w0.z,w0.w,w1.x,w1.y,w1.z,w1.w};
      float bj[8] = {b0.x,b0.y,b0.z,b0.w,b1.x,b1.y,b1.z,b1.w};
      #pragma unroll
      for (int j=0;j<8;++j)
        af[s][ks][j] = (short)f2bf((v[ks*8+j]-mu)*rstd*wj[j] + bj[j]);
    }
  }
  // 6 chunks of 8 nt (48KB each, layout = linear copy of Bp1 chunk)
  for (int c=0;c<6;++c){
    {
      const u16* gsrc = Bp1 + (size_t)c*24576 + wv*3072 + lane*8;
      char* lbase = smem + wv*6144;
      #pragma unroll
      for (int r=0;r<6;++r)
        __builtin_amdgcn_global_load_lds((const AS1 void*)(gsrc + r*512),
                                         (AS3 void*)(lbase + r*1024), 16, 0, 0);
    }
    asm volatile("s_waitcnt vmcnt(0)" ::: "memory");
    __syncthreads();
    #pragma unroll
    for (int ntl=0; ntl<8; ++ntl){
      int nt = c*8 + ntl;
      f32x4 acc0 = (f32x4){0.f,0.f,0.f,0.f};
      f32x4 acc1 = (f32x4){0.f,0.f,0.f,0.f};
      #pragma unroll
      for (int ks=0;ks<6;++ks){
        bf16x8 bf_ = *(const bf16x8*)(smem + ((ntl*6+ks)<<10) + lane*16);
        acc0 = __builtin_amdgcn_mfma_f32_16x16x32_bf16(af[0][ks], bf_, acc0, 0,0,0);
        acc1 = __builtin_amdgcn_mfma_f32_16x16x32_bf16(af[1][ks], bf_, acc1, 0,0,0);
      }
      int col = nt*16 + lr;
      u16* base = (col < DIN) ? xB : zB;
      int cc = (col < DIN) ? col : col - DIN;
      #pragma unroll
      for (int r=0;r<4;++r){
        int row0 = tokw + lq*4 + r;
        base[(size_t)row0*DIN + cc]      = f2bf(acc0[r]);
        base[(size_t)(row0+16)*DIN + cc] = f2bf(acc1[r]);
      }
    }
    __syncthreads();
  }
}

// ---------------- conv3 + SiLU + MFMA projection (also emits uB = silu(conv)) ----------------
__global__ __launch_bounds__(256) void k_conv(const u16* __restrict__ xB,
        const float* __restrict__ cwT, const float* __restrict__ cb,
        const u16* __restrict__ Wxp, float* __restrict__ proj, u16* __restrict__ uB){
  int tid = threadIdx.x, wv = tid>>6, lane = tid&63;
  int lr = lane&15, lq = lane>>4;
  int tok0 = blockIdx.x*64 + wv*16;
  int token = tok0 + lr;
  int l = token % LSEQ;
  float m1 = (l>=1)?1.f:0.f, m2 = (l>=2)?1.f:0.f;
  int tm1 = (l>=1)? token-1 : token;
  int tm2 = (l>=2)? token-2 : token;
  bf16x8 bfrag[12];
  #pragma unroll
  for (int ks=0;ks<12;++ks)
    bfrag[ks] = *(const bf16x8*)(Wxp + (size_t)ks*512 + (size_t)lane*8);
  f32x4 acc = (f32x4){0.f,0.f,0.f,0.f};
  #pragma unroll
  for (int ks=0;ks<12;++ks){
    int ch0 = ks*32 + lq*8;
    bf16x8 x0 = *(const bf16x8*)(xB + (size_t)token*DIN + ch0);
    bf16x8 x1 = *(const bf16x8*)(xB + (size_t)tm1*DIN + ch0);
    bf16x8 x2 = *(const bf16x8*)(xB + (size_t)tm2*DIN + ch0);
    const float* w2 = cwT + 2*DIN + ch0;
    const float* w1 = cwT + 1*DIN + ch0;
    const float* w0 = cwT + 0*DIN + ch0;
    const float* cbp = cb + ch0;
    bf16x8 af;
    #pragma unroll
    for (int j=0;j<8;++j){
      float a = cbp[j] + w2[j]*bf2f((u16)x0[j])
                       + (w1[j]*m1)*bf2f((u16)x1[j])
                       + (w0[j]*m2)*bf2f((u16)x2[j]);
      af[j] = (short)f2bf(silu_f(a));
    }
    *(bf16x8*)(uB + (size_t)token*DIN + ch0) = af;   // u = silu(conv(x)) in bf16
    acc = __builtin_amdgcn_mfma_f32_16x16x32_bf16(af, bfrag[ks], acc, 0,0,0);
  }
  #pragma unroll
  for (int r=0;r<4;++r){
    int row = lq*4 + r;
    proj[(size_t)(tok0+row)*PSTR + lr] = acc[r];
  }
}

// ---------------- scan pass 1 (reads precomputed uB; no conv recompute) ----------------
__global__ __launch_bounds__(384) void k_scan1(const float* __restrict__ proj, const u16* __restrict__ uB,
    const float* __restrict__ Wdt, const float* __restrict__ bdt, const float* __restrict__ Alog,
    float* __restrict__ Pg, float* __restrict__ Hg){
  __shared__ __align__(16) float ps[CHUNK*PSTR];
  int b = blockIdx.y, ch = blockIdx.x, d = threadIdx.x;
  int tok0 = b*LSEQ + ch*CHUNK;
  {
    const float4* src = (const float4*)(proj + (size_t)tok0*PSTR);
    float4* dst = (float4*)ps;
    for (int i = d; i < CHUNK*PSTR/4; i += 384) dst[i] = src[i];
  }
  __syncthreads();
  float wdt[12];
  #pragma unroll
  for (int r=0;r<12;++r) wdt[r] = Wdt[r*DIN+d];
  float bd = bdt[d];
  float Av = -__expf(Alog[d]);
  float h = 0.f, P = 1.f;
  #pragma unroll 4
  for (int il=0; il<CHUNK; ++il){
    float uu = bf2f(uB[(size_t)(tok0+il)*DIN + d]);
    const float4* pq = (const float4*)(ps + il*PSTR);
    float4 q0=pq[0], q1=pq[1], q2=pq[2], q3=pq[3];
    float xv = bd + q0.x*wdt[0]+q0.y*wdt[1]+q0.z*wdt[2]+q0.w*wdt[3]
                  + q1.x*wdt[4]+q1.y*wdt[5]+q1.z*wdt[6]+q1.w*wdt[7]
                  + q2.x*wdt[8]+q2.y*wdt[9]+q2.z*wdt[10]+q2.w*wdt[11];
    float dt = softplus_f(xv);
    float dA = __expf(dt*Av);
    h = dA*h + dt*q3.x*uu;
    P *= dA;
  }
  int o = (b*NCH + ch)*DIN + d;
  Pg[o] = P; Hg[o] = h;
}

// ---------------- scan pass 2 ----------------
__global__ void k_scan2(const float* __restrict__ Pg, const float* __restrict__ Hg,
                        float* __restrict__ hin){
  int idx = blockIdx.x*256 + threadIdx.x;
  int b = idx/DIN, d = idx - b*DIN;
  float run = 0.f;
  #pragma unroll 4
  for (int ch=0; ch<NCH; ++ch){
    int o = (b*NCH+ch)*DIN + d;
    hin[o] = run;
    run = Pg[o]*run + Hg[o];
  }
}

// ---------------- scan pass 3 (reads precomputed uB) ----------------
__global__ __launch_bounds__(384) void k_scan3(const float* __restrict__ proj, const u16* __restrict__ uB,
    const float* __restrict__ Wdt, const float* __restrict__ bdt,
    const float* __restrict__ Alog, const float* __restrict__ Dp,
    const float* __restrict__ hin, u16* __restrict__ zB){
  __shared__ __align__(16) float ps[CHUNK*PSTR];
  int b = blockIdx.y, ch = blockIdx.x, d = threadIdx.x;
  int tok0 = b*LSEQ + ch*CHUNK;
  {
    const float4* src = (const float4*)(proj + (size_t)tok0*PSTR);
    float4* dst = (float4*)ps;
    for (int i = d; i < CHUNK*PSTR/4; i += 384) dst[i] = src[i];
  }
  __syncthreads();
  float wdt[12];
  #pragma unroll
  for (int r=0;r<12;++r) wdt[r] = Wdt[r*DIN+d];
  float bd = bdt[d];
  float Av = -__expf(Alog[d]);
  float Dv = Dp[d];
  float h = hin[(b*NCH+ch)*DIN + d];
  #pragma unroll 4
  for (int il=0; il<CHUNK; ++il){
    float uu = bf2f(uB[(size_t)(tok0+il)*DIN + d]);
    const float4* pq = (const float4*)(ps + il*PSTR);
    float4 q0=pq[0], q1=pq[1], q2=pq[2], q3=pq[3];
    float xv = bd + q0.x*wdt[0]+q0.y*wdt[1]+q0.z*wdt[2]+q0.w*wdt[3]
                  + q1.x*wdt[4]+q1.y*wdt[5]+q1.z*wdt[6]+q1.w*wdt[7]
                  + q2.x*wdt[8]+q2.y*wdt[9]+q2.z*wdt[10]+q2.w*wdt[11];
    float dt = softplus_f(xv);
    float dA = __expf(dt*Av);
    h = dA*h + dt*q3.x*uu;
    size_t zo = (size_t)(tok0+il)*DIN + d;
    float zz = bf2f(zB[zo]);
    zB[zo] = f2bf((h*q3.y + uu*Dv)*silu_f(zz));
  }
}

// ---------------- GEMM2 (LDS-staged B, 8 waves): out = y @ W_out + x ----------------
__global__ __launch_bounds__(512) void k_gemm2(const u16* __restrict__ A, const u16* __restrict__ Bp2,
        const float* __restrict__ R, float* __restrict__ C)
{
  __shared__ __align__(16) char smem[49152];
  int tid = threadIdx.x, wv = tid>>6, lane = tid&63;
  int lr = lane&15, lq = lane>>4;
  int tokw = blockIdx.x*128 + wv*16;
  int token = tokw + lr;
  bf16x8 af[12];
  #pragma unroll
  for (int ks=0;ks<12;++ks)
    af[ks] = *(const bf16x8*)(A + (size_t)token*DIN + ks*32 + lq*8);
  // 3 chunks of 4 nt (48KB each, linear copy of Bp2 chunk)
  for (int c=0;c<3;++c){
    {
      const u16* gsrc = Bp2 + (size_t)c*24576 + wv*3072 + lane*8;
      char* lbase = smem + wv*6144;
      #pragma unroll
      for (int r=0;r<6;++r)
        __builtin_amdgcn_global_load_lds((const AS1 void*)(gsrc + r*512),
                                         (AS3 void*)(lbase + r*1024), 16, 0, 0);
    }
    asm volatile("s_waitcnt vmcnt(0)" ::: "memory");
    __syncthreads();
    #pragma unroll
    for (int ntl=0; ntl<4; ++ntl){
      int nt = c*4 + ntl;
      f32x4 acc = (f32x4){0.f,0.f,0.f,0.f};
      #pragma unroll
      for (int ks=0;ks<12;++ks){
        bf16x8 bf_ = *(const bf16x8*)(smem + ((ntl*12+ks)<<10) + lane*16);
        acc = __builtin_amdgcn_mfma_f32_16x16x32_bf16(af[ks], bf_, acc, 0,0,0);
      }
      int col = nt*16 + lr;
      #pragma unroll
      for (int r=0;r<4;++r){
        int row = tokw + lq*4 + r;
        size_t o = (size_t)row*DIMC + col;
        C[o] = acc[r] + R[o];
      }
    }
    __syncthreads();
  }
}

// ---------------- launch ----------------
extern "C" void kernel_launch(void* const* d_in, const int* in_sizes, int n_in,
                              void* d_out, int out_size, void* d_ws, size_t ws_size,
                              hipStream_t stream) {
  const float* x     = (const float*)d_in[0];
  const float* lnw   = (const float*)d_in[1];
  const float* lnb   = (const float*)d_in[2];
  const float* Win   = (const float*)d_in[3];
  const float* convw = (const float*)d_in[4];
  const float* convb = (const float*)d_in[5];
  const float* Wx    = (const float*)d_in[6];
  const float* Wdt   = (const float*)d_in[7];
  const float* bdt   = (const float*)d_in[8];
  const float* Alog  = (const float*)d_in[9];
  const float* Dp    = (const float*)d_in[10];
  const float* Wout  = (const float*)d_in[11];
  float* out = (float*)d_out;

  char* ws = (char*)d_ws;
  size_t off = 0;
  auto alloc = [&](size_t bytes){ size_t r = off; off += (bytes + 255) & ~(size_t)255; return r; };
  u16*   xB    = (u16*)  (ws + alloc((size_t)NTOK*DIN*2));
  u16*   zB    = (u16*)  (ws + alloc((size_t)NTOK*DIN*2));
  u16*   uB    = (u16*)  (ws + alloc((size_t)NTOK*DIN*2));
  float* proj  = (float*)(ws + alloc((size_t)NTOK*PSTR*4));
  u16*   Bp1   = (u16*)  (ws + alloc((size_t)XZC*DIMC*2));
  u16*   Bp2   = (u16*)  (ws + alloc((size_t)DIN*DIMC*2));
  u16*   Wxp   = (u16*)  (ws + alloc((size_t)12*4*16*8*2));
  float* cwT   = (float*)(ws + alloc((size_t)3*DIN*4));
  float* Pg    = (float*)(ws + alloc((size_t)NBATCH*NCH*DIN*4));
  float* Hg    = (float*)(ws + alloc((size_t)NBATCH*NCH*DIN*4));
  float* hin   = (float*)(ws + alloc((size_t)NBATCH*NCH*DIN*4));

  k_convert<<<576, 256, 0, stream>>>(Win, Wout, Wx, convw, Bp1, Bp2, Wxp, cwT);
  k_lngemm1<<<NTOK/256, 512, 0, stream>>>(x, lnw, lnb, Bp1, xB, zB);
  k_conv<<<NTOK/64, 256, 0, stream>>>(xB, cwT, convb, Wxp, proj, uB);
  {
    dim3 g(NCH, NBATCH);
    k_scan1<<<g, 384, 0, stream>>>(proj, uB, Wdt, bdt, Alog, Pg, Hg);
  }
  k_scan2<<<24, 256, 0, stream>>>(Pg, Hg, hin);
  {
    dim3 g(NCH, NBATCH);
    k_scan3<<<g, 384, 0, stream>>>(proj, uB, Wdt, bdt, Alog, Dp, hin, zB);
  }
  k_gemm2<<<NTOK/128, 512, 0, stream>>>(zB, Bp2, x, out);
}

// Round 4
// 645.736 us; speedup vs baseline: 1.1947x; 1.0389x over previous
//
#include <hip/hip_runtime.h>
#include <math.h>

#define DIMC 192
#define DIN 384
#define XZC 768
#define NPROJ 14
#define PSTR 16
#define LSEQ 9216
#define NBATCH 16
#define NTOK (NBATCH*LSEQ)     // 147456
#define CHUNK 128
#define NCH (LSEQ/CHUNK)       // 72

typedef unsigned short u16;
typedef unsigned int u32;
typedef __attribute__((ext_vector_type(8))) short bf16x8;
typedef __attribute__((ext_vector_type(4))) float f32x4;

#define AS1 __attribute__((address_space(1)))
#define AS3 __attribute__((address_space(3)))

__device__ __forceinline__ float bf2f(u16 a){
  union { u32 u; float f; } v; v.u = ((u32)a)<<16; return v.f;
}
__device__ __forceinline__ u16 f2bf(float f){
  union { u32 u; float f; } v; v.f = f;
  u32 r = v.u + 0x7FFFu + ((v.u>>16)&1u);
  return (u16)(r>>16);
}
__device__ __forceinline__ float frcp(float x){ return __builtin_amdgcn_rcpf(x); }
__device__ __forceinline__ float softplus_f(float x){
  return fmaxf(x, 0.f) + __logf(1.f + __expf(-fabsf(x)));
}
__device__ __forceinline__ float silu_f(float a){
  return a * frcp(1.f + __expf(-a));
}

// ---------------- weight packing ----------------
// Bp1: W_in (192x768) packed in B-fragment order for 16x16x32 MFMA:
//   Bp1[((nt*6+ks)*64+lane)*8+j] = Win[(ks*32+(lane>>4)*8+j)*XZC + nt*16+(lane&15)]
// Bp2: W_out (384x192) likewise with 12 ksteps.
// Wxp: Wx in B-frag order (N=16 pad). cwT[tap][384]: transposed conv weights.
__global__ void k_convert(const float* __restrict__ Win, const float* __restrict__ Wout,
                          const float* __restrict__ Wx, const float* __restrict__ cw,
                          u16* __restrict__ Bp1, u16* __restrict__ Bp2,
                          u16* __restrict__ Wxp, float* __restrict__ cwT){
  int i = blockIdx.x*256 + threadIdx.x;
  if (i < XZC*DIMC){          // 147456
    int j = i&7, lane = (i>>3)&63, rest = i>>9;
    int ks = rest%6, nt = rest/6;
    int k = ks*32 + (lane>>4)*8 + j, n = nt*16 + (lane&15);
    Bp1[i] = f2bf(Win[(size_t)k*XZC + n]);
  }
  if (i < DIN*DIMC){          // 73728
    int j = i&7, lane = (i>>3)&63, rest = i>>9;
    int ks = rest%12, nt = rest/12;
    int k = ks*32 + (lane>>4)*8 + j, n = nt*16 + (lane&15);
    Bp2[i] = f2bf(Wout[(size_t)k*DIMC + n]);
  }
  if (i < 12*4*16*8){
    int j = i&7, n = (i>>3)&15, quad = (i>>7)&3, kstep = i>>9;
    int k = kstep*32 + quad*8 + j;
    Wxp[i] = (n < NPROJ) ? f2bf(Wx[k*NPROJ + n]) : (u16)0;
  }
  if (i < 3*DIN){
    int tap = i / DIN, ch = i - tap*DIN;
    cwT[i] = cw[ch*3 + tap];
  }
}

// ---------------- fused LayerNorm + GEMM1, 3-phase persistent-B ----------------
// Block = 512 thr = 8 waves = 256 tokens. LN done ONCE, A-frags held in
// registers across 3 LDS phases (16 nt x 96KB each) covering all 48 nt.
// x read once; steady loops are barrier-free.
__global__ __launch_bounds__(512) void k_lngemm1(const float* __restrict__ x,
        const float* __restrict__ lnw, const float* __restrict__ lnb,
        const u16* __restrict__ Bp1, u16* __restrict__ xB, u16* __restrict__ zB)
{
  __shared__ __align__(16) char smem[98304];    // 96KB = 16 nt
  int tid = threadIdx.x, wv = tid>>6, lane = tid&63;
  int lr = lane&15, lq = lane>>4;
  int tokw = blockIdx.x*256 + wv*32;
  // ---- issue phase-0 staging (overlaps LN below) ----
  {
    const char* gsrc = (const char*)Bp1 + wv*12288 + lane*16;
    char* ldst = smem + wv*12288;
    #pragma unroll
    for (int r=0;r<12;++r)
      __builtin_amdgcn_global_load_lds((const AS1 void*)(gsrc + r*1024),
                                       (AS3 void*)(ldst + r*1024), 16, 0, 0);
  }
  // ---- LayerNorm + A-fragment build (2 sets of 16 tokens), regs persist ----
  bf16x8 af[2][6];
  #pragma unroll
  for (int s=0;s<2;++s){
    int token = tokw + s*16 + lr;
    const float* xp = x + (size_t)token*DIMC + lq*8;
    float v[48];
    #pragma unroll
    for (int ks=0;ks<6;++ks){
      float4 a = *(const float4*)(xp + ks*32);
      float4 b = *(const float4*)(xp + ks*32 + 4);
      v[ks*8+0]=a.x; v[ks*8+1]=a.y; v[ks*8+2]=a.z; v[ks*8+3]=a.w;
      v[ks*8+4]=b.x; v[ks*8+5]=b.y; v[ks*8+6]=b.z; v[ks*8+7]=b.w;
    }
    float sm = 0.f;
    #pragma unroll
    for (int j=0;j<48;++j) sm += v[j];
    sm += __shfl_xor(sm, 16); sm += __shfl_xor(sm, 32);
    float mu = sm * (1.0f/DIMC);
    float q = 0.f;
    #pragma unroll
    for (int j=0;j<48;++j){ float d = v[j]-mu; q += d*d; }
    q += __shfl_xor(q, 16); q += __shfl_xor(q, 32);
    float rstd = rsqrtf(q*(1.0f/DIMC) + 1e-5f);
    #pragma unroll
    for (int ks=0;ks<6;++ks){
      const float* wp = lnw + lq*8 + ks*32;
      const float* bp = lnb + lq*8 + ks*32;
      float4 w0 = *(const float4*)(wp),   w1 = *(const float4*)(wp+4);
      float4 b0 = *(const float4*)(bp),   b1 = *(const float4*)(bp+4);
      float wj[8] = {w0.x,w0.y,w0.z,w0.w,w1.x,w1.y,w1.z,w1.w};
      float bj[8] = {b0.x,b0.y,b0.z,b0.w,b1.x,b1.y,b1.z,b1.w};
      #pragma unroll
      for (int j=0;j<8;++j)
        af[s][ks][j] = (short)f2bf((v[ks*8+j]-mu)*rstd*wj[j] + bj[j]);
    }
  }
  // ---- 3 phases of 16 nt each ----
  for (int p=0; p<3; ++p){
    if (p){
      __syncthreads();                           // all waves done reading smem
      const char* gsrc = (const char*)Bp1 + (size_t)p*98304 + wv*12288 + lane*16;
      char* ldst = smem + wv*12288;
      #pragma unroll
      for (int r=0;r<12;++r)
        __builtin_amdgcn_global_load_lds((const AS1 void*)(gsrc + r*1024),
                                         (AS3 void*)(ldst + r*1024), 16, 0, 0);
    }
    asm volatile("s_waitcnt vmcnt(0)" ::: "memory");
    __syncthreads();
    #pragma unroll 2
    for (int ntl=0; ntl<16; ++ntl){
      f32x4 acc0 = (f32x4){0.f,0.f,0.f,0.f};
      f32x4 acc1 = (f32x4){0.f,0.f,0.f,0.f};
      #pragma unroll
      for (int ks=0;ks<6;++ks){
        bf16x8 bf_ = *(const bf16x8*)(smem + ((ntl*6+ks)<<10) + lane*16);
        acc0 = __builtin_amdgcn_mfma_f32_16x16x32_bf16(af[0][ks], bf_, acc0, 0,0,0);
        acc1 = __builtin_amdgcn_mfma_f32_16x16x32_bf16(af[1][ks], bf_, acc1, 0,0,0);
      }
      int col = (p*16 + ntl)*16 + lr;
      u16* base = (col < DIN) ? xB : zB;
      int cc = (col < DIN) ? col : col - DIN;
      #pragma unroll
      for (int r=0;r<4;++r){
        int row0 = tokw + lq*4 + r;
        base[(size_t)row0*DIN + cc]      = f2bf(acc0[r]);
        base[(size_t)(row0+16)*DIN + cc] = f2bf(acc1[r]);
      }
    }
  }
}

// ---------------- conv3 + SiLU + MFMA projection (also emits uB = silu(conv)) ----------------
__global__ __launch_bounds__(256) void k_conv(const u16* __restrict__ xB,
        const float* __restrict__ cwT, const float* __restrict__ cb,
        const u16* __restrict__ Wxp, float* __restrict__ proj, u16* __restrict__ uB){
  int tid = threadIdx.x, wv = tid>>6, lane = tid&63;
  int lr = lane&15, lq = lane>>4;
  int tok0 = blockIdx.x*64 + wv*16;
  int token = tok0 + lr;
  int l = token % LSEQ;
  float m1 = (l>=1)?1.f:0.f, m2 = (l>=2)?1.f:0.f;
  int tm1 = (l>=1)? token-1 : token;
  int tm2 = (l>=2)? token-2 : token;
  bf16x8 bfrag[12];
  #pragma unroll
  for (int ks=0;ks<12;++ks)
    bfrag[ks] = *(const bf16x8*)(Wxp + (size_t)ks*512 + (size_t)lane*8);
  f32x4 acc = (f32x4){0.f,0.f,0.f,0.f};
  #pragma unroll
  for (int ks=0;ks<12;++ks){
    int ch0 = ks*32 + lq*8;
    bf16x8 x0 = *(const bf16x8*)(xB + (size_t)token*DIN + ch0);
    bf16x8 x1 = *(const bf16x8*)(xB + (size_t)tm1*DIN + ch0);
    bf16x8 x2 = *(const bf16x8*)(xB + (size_t)tm2*DIN + ch0);
    const float* w2 = cwT + 2*DIN + ch0;
    const float* w1 = cwT + 1*DIN + ch0;
    const float* w0 = cwT + 0*DIN + ch0;
    const float* cbp = cb + ch0;
    bf16x8 af;
    #pragma unroll
    for (int j=0;j<8;++j){
      float a = cbp[j] + w2[j]*bf2f((u16)x0[j])
                       + (w1[j]*m1)*bf2f((u16)x1[j])
                       + (w0[j]*m2)*bf2f((u16)x2[j]);
      af[j] = (short)f2bf(silu_f(a));
    }
    *(bf16x8*)(uB + (size_t)token*DIN + ch0) = af;   // u = silu(conv(x)) in bf16
    acc = __builtin_amdgcn_mfma_f32_16x16x32_bf16(af, bfrag[ks], acc, 0,0,0);
  }
  #pragma unroll
  for (int r=0;r<4;++r){
    int row = lq*4 + r;
    proj[(size_t)(tok0+row)*PSTR + lr] = acc[r];
  }
}

// ---------------- scan pass 1 (reads precomputed uB; no conv recompute) ----------------
__global__ __launch_bounds__(384) void k_scan1(const float* __restrict__ proj, const u16* __restrict__ uB,
    const float* __restrict__ Wdt, const float* __restrict__ bdt, const float* __restrict__ Alog,
    float* __restrict__ Pg, float* __restrict__ Hg){
  __shared__ __align__(16) float ps[CHUNK*PSTR];
  int b = blockIdx.y, ch = blockIdx.x, d = threadIdx.x;
  int tok0 = b*LSEQ + ch*CHUNK;
  {
    const float4* src = (const float4*)(proj + (size_t)tok0*PSTR);
    float4* dst = (float4*)ps;
    for (int i = d; i < CHUNK*PSTR/4; i += 384) dst[i] = src[i];
  }
  __syncthreads();
  float wdt[12];
  #pragma unroll
  for (int r=0;r<12;++r) wdt[r] = Wdt[r*DIN+d];
  float bd = bdt[d];
  float Av = -__expf(Alog[d]);
  float h = 0.f, P = 1.f;
  #pragma unroll 4
  for (int il=0; il<CHUNK; ++il){
    float uu = bf2f(uB[(size_t)(tok0+il)*DIN + d]);
    const float4* pq = (const float4*)(ps + il*PSTR);
    float4 q0=pq[0], q1=pq[1], q2=pq[2], q3=pq[3];
    float xv = bd + q0.x*wdt[0]+q0.y*wdt[1]+q0.z*wdt[2]+q0.w*wdt[3]
                  + q1.x*wdt[4]+q1.y*wdt[5]+q1.z*wdt[6]+q1.w*wdt[7]
                  + q2.x*wdt[8]+q2.y*wdt[9]+q2.z*wdt[10]+q2.w*wdt[11];
    float dt = softplus_f(xv);
    float dA = __expf(dt*Av);
    h = dA*h + dt*q3.x*uu;
    P *= dA;
  }
  int o = (b*NCH + ch)*DIN + d;
  Pg[o] = P; Hg[o] = h;
}

// ---------------- scan pass 2 ----------------
__global__ void k_scan2(const float* __restrict__ Pg, const float* __restrict__ Hg,
                        float* __restrict__ hin){
  int idx = blockIdx.x*256 + threadIdx.x;
  int b = idx/DIN, d = idx - b*DIN;
  float run = 0.f;
  #pragma unroll 4
  for (int ch=0; ch<NCH; ++ch){
    int o = (b*NCH+ch)*DIN + d;
    hin[o] = run;
    run = Pg[o]*run + Hg[o];
  }
}

// ---------------- scan pass 3 (reads precomputed uB) ----------------
__global__ __launch_bounds__(384) void k_scan3(const float* __restrict__ proj, const u16* __restrict__ uB,
    const float* __restrict__ Wdt, const float* __restrict__ bdt,
    const float* __restrict__ Alog, const float* __restrict__ Dp,
    const float* __restrict__ hin, u16* __restrict__ zB){
  __shared__ __align__(16) float ps[CHUNK*PSTR];
  int b = blockIdx.y, ch = blockIdx.x, d = threadIdx.x;
  int tok0 = b*LSEQ + ch*CHUNK;
  {
    const float4* src = (const float4*)(proj + (size_t)tok0*PSTR);
    float4* dst = (float4*)ps;
    for (int i = d; i < CHUNK*PSTR/4; i += 384) dst[i] = src[i];
  }
  __syncthreads();
  float wdt[12];
  #pragma unroll
  for (int r=0;r<12;++r) wdt[r] = Wdt[r*DIN+d];
  float bd = bdt[d];
  float Av = -__expf(Alog[d]);
  float Dv = Dp[d];
  float h = hin[(b*NCH+ch)*DIN + d];
  #pragma unroll 4
  for (int il=0; il<CHUNK; ++il){
    float uu = bf2f(uB[(size_t)(tok0+il)*DIN + d]);
    const float4* pq = (const float4*)(ps + il*PSTR);
    float4 q0=pq[0], q1=pq[1], q2=pq[2], q3=pq[3];
    float xv = bd + q0.x*wdt[0]+q0.y*wdt[1]+q0.z*wdt[2]+q0.w*wdt[3]
                  + q1.x*wdt[4]+q1.y*wdt[5]+q1.z*wdt[6]+q1.w*wdt[7]
                  + q2.x*wdt[8]+q2.y*wdt[9]+q2.z*wdt[10]+q2.w*wdt[11];
    float dt = softplus_f(xv);
    float dA = __expf(dt*Av);
    h = dA*h + dt*q3.x*uu;
    size_t zo = (size_t)(tok0+il)*DIN + d;
    float zz = bf2f(zB[zo]);
    zB[zo] = f2bf((h*q3.y + uu*Dv)*silu_f(zz));
  }
}

// ---------------- GEMM2, 2-phase persistent-B (96KB+48KB): out = y @ W_out + x ----------------
// Block = 512 thr = 8 waves = 128 tokens (16/wave). Grid 1152 for balance.
__global__ __launch_bounds__(512) void k_gemm2(const u16* __restrict__ A, const u16* __restrict__ Bp2,
        const float* __restrict__ R, float* __restrict__ C)
{
  __shared__ __align__(16) char smem[98304];    // 96KB = 8 nt (phase A); 4 nt reuse (phase B)
  int tid = threadIdx.x, wv = tid>>6, lane = tid&63;
  int lr = lane&15, lq = lane>>4;
  int tokw = blockIdx.x*128 + wv*16;
  int token = tokw + lr;
  // ---- issue phase-A staging (8 nt = 96KB) ----
  {
    const char* gsrc = (const char*)Bp2 + wv*12288 + lane*16;
    char* ldst = smem + wv*12288;
    #pragma unroll
    for (int r=0;r<12;++r)
      __builtin_amdgcn_global_load_lds((const AS1 void*)(gsrc + r*1024),
                                       (AS3 void*)(ldst + r*1024), 16, 0, 0);
  }
  bf16x8 af[12];
  #pragma unroll
  for (int ks=0;ks<12;++ks)
    af[ks] = *(const bf16x8*)(A + (size_t)token*DIN + ks*32 + lq*8);
  asm volatile("s_waitcnt vmcnt(0)" ::: "memory");
  __syncthreads();
  #pragma unroll 2
  for (int nt=0; nt<8; ++nt){
    f32x4 acc = (f32x4){0.f,0.f,0.f,0.f};
    #pragma unroll
    for (int ks=0;ks<12;++ks){
      bf16x8 bf_ = *(const bf16x8*)(smem + ((nt*12+ks)<<10) + lane*16);
      acc = __builtin_amdgcn_mfma_f32_16x16x32_bf16(af[ks], bf_, acc, 0,0,0);
    }
    int col = nt*16 + lr;
    #pragma unroll
    for (int r=0;r<4;++r){
      int row = tokw + lq*4 + r;
      size_t o = (size_t)row*DIMC + col;
      C[o] = acc[r] + R[o];
    }
  }
  __syncthreads();                               // all waves done with phase A
  {
    const char* gsrc = (const char*)Bp2 + 98304 + wv*6144 + lane*16;
    char* ldst = smem + wv*6144;
    #pragma unroll
    for (int r=0;r<6;++r)
      __builtin_amdgcn_global_load_lds((const AS1 void*)(gsrc + r*1024),
                                       (AS3 void*)(ldst + r*1024), 16, 0, 0);
  }
  asm volatile("s_waitcnt vmcnt(0)" ::: "memory");
  __syncthreads();
  #pragma unroll 2
  for (int nt=8; nt<12; ++nt){
    f32x4 acc = (f32x4){0.f,0.f,0.f,0.f};
    #pragma unroll
    for (int ks=0;ks<12;++ks){
      bf16x8 bf_ = *(const bf16x8*)(smem + (((nt-8)*12+ks)<<10) + lane*16);
      acc = __builtin_amdgcn_mfma_f32_16x16x32_bf16(af[ks], bf_, acc, 0,0,0);
    }
    int col = nt*16 + lr;
    #pragma unroll
    for (int r=0;r<4;++r){
      int row = tokw + lq*4 + r;
      size_t o = (size_t)row*DIMC + col;
      C[o] = acc[r] + R[o];
    }
  }
}

// ---------------- launch ----------------
extern "C" void kernel_launch(void* const* d_in, const int* in_sizes, int n_in,
                              void* d_out, int out_size, void* d_ws, size_t ws_size,
                              hipStream_t stream) {
  const float* x     = (const float*)d_in[0];
  const float* lnw   = (const float*)d_in[1];
  const float* lnb   = (const float*)d_in[2];
  const float* Win   = (const float*)d_in[3];
  const float* convw = (const float*)d_in[4];
  const float* convb = (const float*)d_in[5];
  const float* Wx    = (const float*)d_in[6];
  const float* Wdt   = (const float*)d_in[7];
  const float* bdt   = (const float*)d_in[8];
  const float* Alog  = (const float*)d_in[9];
  const float* Dp    = (const float*)d_in[10];
  const float* Wout  = (const float*)d_in[11];
  float* out = (float*)d_out;

  char* ws = (char*)d_ws;
  size_t off = 0;
  auto alloc = [&](size_t bytes){ size_t r = off; off += (bytes + 255) & ~(size_t)255; return r; };
  u16*   xB    = (u16*)  (ws + alloc((size_t)NTOK*DIN*2));
  u16*   zB    = (u16*)  (ws + alloc((size_t)NTOK*DIN*2));
  u16*   uB    = (u16*)  (ws + alloc((size_t)NTOK*DIN*2));
  float* proj  = (float*)(ws + alloc((size_t)NTOK*PSTR*4));
  u16*   Bp1   = (u16*)  (ws + alloc((size_t)XZC*DIMC*2));
  u16*   Bp2   = (u16*)  (ws + alloc((size_t)DIN*DIMC*2));
  u16*   Wxp   = (u16*)  (ws + alloc((size_t)12*4*16*8*2));
  float* cwT   = (float*)(ws + alloc((size_t)3*DIN*4));
  float* Pg    = (float*)(ws + alloc((size_t)NBATCH*NCH*DIN*4));
  float* Hg    = (float*)(ws + alloc((size_t)NBATCH*NCH*DIN*4));
  float* hin   = (float*)(ws + alloc((size_t)NBATCH*NCH*DIN*4));

  k_convert<<<576, 256, 0, stream>>>(Win, Wout, Wx, convw, Bp1, Bp2, Wxp, cwT);
  k_lngemm1<<<NTOK/256, 512, 0, stream>>>(x, lnw, lnb, Bp1, xB, zB);
  k_conv<<<NTOK/64, 256, 0, stream>>>(xB, cwT, convb, Wxp, proj, uB);
  {
    dim3 g(NCH, NBATCH);
    k_scan1<<<g, 384, 0, stream>>>(proj, uB, Wdt, bdt, Alog, Pg, Hg);
  }
  k_scan2<<<24, 256, 0, stream>>>(Pg, Hg, hin);
  {
    dim3 g(NCH, NBATCH);
    k_scan3<<<g, 384, 0, stream>>>(proj, uB, Wdt, bdt, Alog, Dp, hin, zB);
  }
  k_gemm2<<<NTOK/128, 512, 0, stream>>>(zB, Bp2, x, out);
}